// Round 2
// baseline (353.671 us; speedup 1.0000x reference)
//
#include <hip/hip_runtime.h>
#include <hip/hip_bf16.h>

typedef __bf16 bf16_t;
typedef __attribute__((ext_vector_type(8))) __bf16 bf16x8;
typedef __attribute__((ext_vector_type(4))) float f32x4;

// ------- pack B[K,N] f32 -> bf16 MFMA fragments ---------------------------
__device__ inline void packB_one(const float* __restrict__ B, bf16_t* __restrict__ Bp,
                                 int N, int idx) {
    int j    = idx & 7;
    int lane = (idx >> 3) & 63;
    int st   = idx >> 9;
    int nt   = N >> 4;
    int s = st / nt, t = st - s * nt;
    int k = s * 32 + (lane >> 4) * 8 + j;
    int n = t * 16 + (lane & 15);
    Bp[idx] = (bf16_t)B[(size_t)k * N + n];
}

// ------- fused front-end: A-pack + weight pack + degree count -------------
// blocks [0, APACK): feat f32 -> bf16 in MFMA fragment order
//   Ap[((strip*8 + s)*64 + lane)*8 + j] = feat[strip*16+(lane&15)][(lane>>4)*8+s*32+j]
//   reads: per instr 16 rows x 128B contiguous (line-complete)
//   writes: per instr 1KB contiguous
// blocks [APACK, APACK+144): weight packs
// blocks [APACK+144, ...): degree histogram, 4 edges/thread
__global__ __launch_bounds__(256) void k_front(
        const float* __restrict__ feat, bf16_t* __restrict__ Ap,
        const float* __restrict__ W1, bf16_t* __restrict__ Bp1,
        const float* __restrict__ W2, bf16_t* __restrict__ Bp2,
        const int* __restrict__ dst, int* __restrict__ deg,
        int N_nodes, int E, int APACK_BLOCKS) {
    int b = blockIdx.x, t = threadIdx.x;
    if (b < APACK_BLOCKS) {
        int idx = b * 256 + t;
        if (idx >= N_nodes * 64) return;       // 16 rows per wave of 64 lanes
        int w    = idx >> 6;                   // strip
        int lane = idx & 63;
        int r16 = lane & 15, quad = lane >> 4;
        const float* arow = feat + (size_t)(w * 16 + r16) * 256 + quad * 8;
        bf16_t* opb = Ap + (size_t)w * 4096 + lane * 8;   // (w*8+s)*512 + lane*8
#pragma unroll
        for (int s = 0; s < 8; ++s) {
            const float* ap = arow + s * 32;
            bf16x8 a;
#pragma unroll
            for (int j = 0; j < 8; ++j) a[j] = (bf16_t)ap[j];
            *(bf16x8*)(opb + s * 512) = a;
        }
        return;
    }
    b -= APACK_BLOCKS;
    const int PACK_BLOCKS = (32768 + 4096) / 256;   // 144
    if (b < PACK_BLOCKS) {
        int idx = b * 256 + t;
        if (idx < 32768) packB_one(W1, Bp1, 128, idx);
        else             packB_one(W2, Bp2, 32, idx - 32768);
        return;
    }
    int i = (b - PACK_BLOCKS) * 1024 + t * 4;
    if (i + 4 <= E) {
        int4 v = *(const int4*)(dst + i);
        atomicAdd(&deg[v.x], 1); atomicAdd(&deg[v.y], 1);
        atomicAdd(&deg[v.z], 1); atomicAdd(&deg[v.w], 1);
    } else {
#pragma unroll
        for (int j = 0; j < 4; ++j)
            if (i + j < E) atomicAdd(&deg[dst[i + j]], 1);
    }
}

// ---------------- dinv + scan phase 1 (fused) -----------------------------
__global__ __launch_bounds__(256) void k_dinv_scan1(const int* __restrict__ deg,
                                                    float* __restrict__ dinv,
                                                    int* __restrict__ bsum, int n) {
    __shared__ int red[256];
    int b = blockIdx.x, t = threadIdx.x;
    int base = b * 1024 + t * 4;
    int s = 0;
#pragma unroll
    for (int j = 0; j < 4; ++j) {
        int i = base + j;
        if (i < n) { int d = deg[i]; s += d; dinv[i] = rsqrtf((float)(d + 1)); }
    }
    red[t] = s;
    __syncthreads();
    for (int d = 128; d > 0; d >>= 1) {
        if (t < d) red[t] += red[t + d];
        __syncthreads();
    }
    if (t == 0) bsum[b] = red[0];
}

// phase 2: single block scans <=256 block sums (exclusive), writes rowPtr[n]=E
__global__ __launch_bounds__(256) void k_scan2(int* __restrict__ bsum, int nb,
                                               int* __restrict__ rowPtr, int n) {
    __shared__ int s[256];
    int t = threadIdx.x;
    int v = (t < nb) ? bsum[t] : 0;
    s[t] = v;
    __syncthreads();
    for (int d = 1; d < 256; d <<= 1) {   // Hillis-Steele inclusive
        int u = (t >= d) ? s[t - d] : 0;
        __syncthreads();
        s[t] += u;
        __syncthreads();
    }
    if (t < nb) bsum[t] = s[t] - v;       // exclusive block offset
    if (t == 255) rowPtr[n] = s[255];     // total = E
}

// phase 3: block-local exclusive scan + block offset -> rowPtr AND cursor
__global__ __launch_bounds__(256) void k_scan3(const int* __restrict__ deg,
                                               const int* __restrict__ bsum,
                                               int* __restrict__ rowPtr,
                                               int* __restrict__ cursor, int n) {
    __shared__ int red[256];
    int b = blockIdx.x, t = threadIdx.x;
    int base = b * 1024 + t * 4;
    int v[4]; int s = 0;
#pragma unroll
    for (int j = 0; j < 4; ++j) { int i = base + j; v[j] = (i < n) ? deg[i] : 0; s += v[j]; }
    red[t] = s;
    __syncthreads();
    for (int d = 1; d < 256; d <<= 1) {
        int u = (t >= d) ? red[t - d] : 0;
        __syncthreads();
        red[t] += u;
        __syncthreads();
    }
    int run = bsum[b] + red[t] - s;
#pragma unroll
    for (int j = 0; j < 4; ++j) {
        int i = base + j;
        if (i < n) { rowPtr[i] = run; cursor[i] = run; run += v[j]; }
    }
}

// ------- fused: packed-A GEMM + edge scatter (independent work) -----------
// A is pre-packed in fragment order: per step one contiguous bf16x8 per lane.
template <int KSTEPS, int NTILES>
__global__ __launch_bounds__(256) void k_gemm_scatter(
        const bf16_t* __restrict__ Ap, const bf16_t* __restrict__ Bp,
        bf16_t* __restrict__ C, int M, int gemmBlocks,
        const int* __restrict__ src, const int* __restrict__ dst,
        const float* __restrict__ dinv, int* __restrict__ cursor,
        int2* __restrict__ edata, int E) {
    int b = blockIdx.x, t = threadIdx.x;
    if (b < gemmBlocks) {
        int wave = (b * 256 + t) >> 6;
        if (wave * 16 >= M) return;
        int lane = t & 63;
        int r16 = lane & 15, quad = lane >> 4;
        const int N = NTILES * 16;
        f32x4 acc[NTILES] = {};
        const bf16_t* apb = Ap + (size_t)wave * (KSTEPS * 512) + lane * 8;
#pragma unroll
        for (int s = 0; s < KSTEPS; ++s) {
            bf16x8 a = *(const bf16x8*)(apb + s * 512);
            const bf16_t* bp = Bp + ((size_t)(s * NTILES) * 64 + lane) * 8;
#pragma unroll
            for (int tt = 0; tt < NTILES; ++tt) {
                bf16x8 bb = *(const bf16x8*)(bp + tt * 512);
                acc[tt] = __builtin_amdgcn_mfma_f32_16x16x32_bf16(a, bb, acc[tt], 0, 0, 0);
            }
        }
#pragma unroll
        for (int tt = 0; tt < NTILES; ++tt)
#pragma unroll
            for (int r = 0; r < 4; ++r)
                C[(size_t)(wave * 16 + quad * 4 + r) * N + tt * 16 + r16] = (bf16_t)acc[tt][r];
        return;
    }
    int e = (b - gemmBlocks) * 256 + t;
    if (e >= E) return;
    int s = src[e], d = dst[e];
    int pos = atomicAdd(&cursor[d], 1);   // cursor pre-seeded with rowPtr
    int2 p; p.x = s; p.y = __float_as_int(dinv[s] * dinv[d]);
    edata[pos] = p;
}

// ------- packed-A GEMM (layer 2) ------------------------------------------
template <int KSTEPS, int NTILES>
__global__ __launch_bounds__(256) void k_gemm_p(
        const bf16_t* __restrict__ Ap, const bf16_t* __restrict__ Bp,
        bf16_t* __restrict__ C, int M) {
    int wave = (blockIdx.x * blockDim.x + threadIdx.x) >> 6;
    if (wave * 16 >= M) return;
    int lane = threadIdx.x & 63;
    int r16 = lane & 15, quad = lane >> 4;
    const int N = NTILES * 16;
    f32x4 acc[NTILES] = {};
    const bf16_t* apb = Ap + (size_t)wave * (KSTEPS * 512) + lane * 8;
#pragma unroll
    for (int s = 0; s < KSTEPS; ++s) {
        bf16x8 a = *(const bf16x8*)(apb + s * 512);
        const bf16_t* bp = Bp + ((size_t)(s * NTILES) * 64 + lane) * 8;
#pragma unroll
        for (int t = 0; t < NTILES; ++t) {
            bf16x8 b = *(const bf16x8*)(bp + t * 512);
            acc[t] = __builtin_amdgcn_mfma_f32_16x16x32_bf16(a, b, acc[t], 0, 0, 0);
        }
    }
#pragma unroll
    for (int t = 0; t < NTILES; ++t)
#pragma unroll
        for (int r = 0; r < 4; ++r)
            C[(size_t)(wave * 16 + quad * 4 + r) * N + t * 16 + r16] = (bf16_t)acc[t][r];
}

// ------- layer-1 aggregate: writes H directly in packed fragment layout ---
// H row = node `wave`; lane q (q<16) holds features f = q*8 .. q*8+8.
// Packed pos for layer-2 GEMM (K=128, KSTEPS=4):
//   strip=wave>>4, s=q>>2, l2=(wave&15)+16*(q&3)
//   Hp[((strip*4 + s)*64 + l2)*8 + j]
__global__ __launch_bounds__(256) void k_agg1(
        const int* __restrict__ rowPtr, const int2* __restrict__ edata,
        const bf16_t* __restrict__ XW1, const float* __restrict__ dinv,
        const float* __restrict__ b1, bf16_t* __restrict__ Hp, int n) {
    int wave = (blockIdx.x * blockDim.x + threadIdx.x) >> 6;
    if (wave >= n) return;
    int lane = threadIdx.x & 63;
    int fl = (lane & 15) << 3;   // 8 features
    int h  = lane >> 4;          // parity stream 0..3
    int r0 = rowPtr[wave], r1 = rowPtr[wave + 1];
    float a0[8] = {}, a1[8] = {};
    int k = r0 + h;
    for (; k + 4 < r1; k += 8) {          // 2 independent gathers in flight
        int2 e0 = edata[k], e1 = edata[k + 4];
        float w0 = __int_as_float(e0.y), w1 = __int_as_float(e1.y);
        bf16x8 x0 = *(const bf16x8*)(XW1 + ((size_t)e0.x << 7) + fl);
        bf16x8 x1 = *(const bf16x8*)(XW1 + ((size_t)e1.x << 7) + fl);
#pragma unroll
        for (int j = 0; j < 8; ++j) { a0[j] += (float)x0[j] * w0; a1[j] += (float)x1[j] * w1; }
    }
    if (k < r1) {
        int2 e0 = edata[k];
        float w0 = __int_as_float(e0.y);
        bf16x8 x0 = *(const bf16x8*)(XW1 + ((size_t)e0.x << 7) + fl);
#pragma unroll
        for (int j = 0; j < 8; ++j) a0[j] += (float)x0[j] * w0;
    }
#pragma unroll
    for (int j = 0; j < 8; ++j) {        // convergent reduction over 4 streams
        a0[j] += a1[j];
        a0[j] += __shfl_xor(a0[j], 16);
        a0[j] += __shfl_xor(a0[j], 32);
    }
    if (h == 0) {
        float d = dinv[wave], d2 = d * d;
        bf16x8 xs = *(const bf16x8*)(XW1 + ((size_t)wave << 7) + fl);
        bf16x8 hv;
#pragma unroll
        for (int j = 0; j < 8; ++j) {
            float v = a0[j] + (float)xs[j] * d2 + b1[fl + j];
            hv[j] = (bf16_t)fmaxf(v, 0.f);
        }
        int q = lane & 15;
        size_t off = (((size_t)(wave >> 4) * 4 + (q >> 2)) * 64
                      + (wave & 15) + 16 * (q & 3)) * 8;
        *(bf16x8*)(Hp + off) = hv;
    }
}

// ------- layer-2 aggregate + log_softmax ----------------------------------
__global__ __launch_bounds__(256) void k_agg2(
        const int* __restrict__ rowPtr, const int2* __restrict__ edata,
        const bf16_t* __restrict__ XW2, const float* __restrict__ dinv,
        const float* __restrict__ b2, float* __restrict__ out, int n) {
    int wave = (blockIdx.x * blockDim.x + threadIdx.x) >> 6;
    if (wave >= n) return;
    int lane = threadIdx.x & 63;
    int g = lane & 15;           // class pair: {2g, 2g+1}
    int h = lane >> 4;           // stream 0..3
    int r0 = rowPtr[wave], r1 = rowPtr[wave + 1];
    float a00 = 0.f, a01 = 0.f, a10 = 0.f, a11 = 0.f;
    int k = r0 + h;
    for (; k + 4 < r1; k += 8) {
        int2 e0 = edata[k], e1 = edata[k + 4];
        float w0 = __int_as_float(e0.y), w1 = __int_as_float(e1.y);
        unsigned p0 = *(const unsigned*)(XW2 + ((size_t)e0.x << 5) + 2 * g);
        unsigned p1 = *(const unsigned*)(XW2 + ((size_t)e1.x << 5) + 2 * g);
        a00 += __int_as_float(p0 << 16) * w0;
        a01 += __int_as_float(p0 & 0xffff0000u) * w0;
        a10 += __int_as_float(p1 << 16) * w1;
        a11 += __int_as_float(p1 & 0xffff0000u) * w1;
    }
    if (k < r1) {
        int2 e0 = edata[k];
        float w0 = __int_as_float(e0.y);
        unsigned p0 = *(const unsigned*)(XW2 + ((size_t)e0.x << 5) + 2 * g);
        a00 += __int_as_float(p0 << 16) * w0;
        a01 += __int_as_float(p0 & 0xffff0000u) * w0;
    }
    float v0 = a00 + a10, v1 = a01 + a11;
    v0 += __shfl_xor(v0, 16); v0 += __shfl_xor(v0, 32);   // combine 4 streams
    v1 += __shfl_xor(v1, 16); v1 += __shfl_xor(v1, 32);
    float d = dinv[wave], d2 = d * d;
    unsigned ps = *(const unsigned*)(XW2 + ((size_t)wave << 5) + 2 * g);
    float2 bb = *(const float2*)(b2 + 2 * g);
    v0 += __int_as_float(ps << 16) * d2 + bb.x;
    v1 += __int_as_float(ps & 0xffff0000u) * d2 + bb.y;
    float mx = fmaxf(v0, v1);
#pragma unroll
    for (int m = 8; m >= 1; m >>= 1) mx = fmaxf(mx, __shfl_xor(mx, m));
    float s = expf(v0 - mx) + expf(v1 - mx);
#pragma unroll
    for (int m = 8; m >= 1; m >>= 1) s += __shfl_xor(s, m);
    if (h == 0) {
        float ls = logf(s);
        float2 o; o.x = v0 - mx - ls; o.y = v1 - mx - ls;
        *(float2*)(out + ((size_t)wave << 5) + 2 * g) = o;
    }
}

extern "C" void kernel_launch(void* const* d_in, const int* in_sizes, int n_in,
                              void* d_out, int out_size, void* d_ws, size_t ws_size,
                              hipStream_t stream) {
    const float* feat = (const float*)d_in[0];
    const int*   eidx = (const int*)d_in[1];
    const float* W1   = (const float*)d_in[2];
    const float* b1   = (const float*)d_in[3];
    const float* W2   = (const float*)d_in[4];
    const float* b2   = (const float*)d_in[5];
    float* out = (float*)d_out;

    const int FIN = 256, HID = 128, NCLS = 32;
    const int N = in_sizes[0] / FIN;   // 100000
    const int E = in_sizes[1] / 2;     // 800000
    const int* src = eidx;
    const int* dst = eidx + E;

    // workspace carve-up (256B aligned)
    char* ws = (char*)d_ws;
    size_t o = 0;
    auto alloc = [&](size_t bytes) -> void* {
        void* p = ws + o;
        o = (o + bytes + 255) & ~(size_t)255;
        return p;
    };
    int*    deg    = (int*)   alloc((size_t)N * 4);
    int*    cursor = (int*)   alloc((size_t)N * 4);   // seeded by k_scan3
    float*  dinv   = (float*) alloc((size_t)N * 4);
    int*    rowPtr = (int*)   alloc((size_t)(N + 1) * 4);
    int*    bsum   = (int*)   alloc(256 * 4);
    bf16_t* Bp1    = (bf16_t*)alloc((size_t)(FIN / 32) * (HID / 16) * 512 * 2);
    bf16_t* Bp2    = (bf16_t*)alloc((size_t)(HID / 32) * (NCLS / 16) * 512 * 2);
    int2*   edata  = (int2*)  alloc((size_t)E * 8);         // 6.4 MB
    bf16_t* Ap1    = (bf16_t*)alloc((size_t)N * FIN * 2);   // 51.2 MB packed feat
    bf16_t* XW1    = (bf16_t*)alloc((size_t)N * HID * 2);   // 25.6 MB
    bf16_t* Hp     = (bf16_t*)alloc((size_t)N * HID * 2);   // 25.6 MB packed H
    bf16_t* XW2    = XW1;   // alias: XW1 dead after k_agg1

    const int T = 256;
    const int NB = (N + 1023) >> 10;                 // 98 scan blocks (<=256)
    const int APACK_BLOCKS = (N * 64 + T - 1) / T;   // 25000 waves-worth? no: N*4 waves... (N/16 waves * 64 thr)
    // strips = N/16 = 6250 waves -> 6250*64/256 = 1563 blocks
    const int AB = ((N / 16) * 64 + T - 1) / T;      // 1563
    const int PACK_BLOCKS = (32768 + 4096) / 256;    // 144
    const int DEG_BLOCKS  = (E + 1023) / 1024;       // 782 (4 edges/thread)
    hipMemsetAsync(deg, 0, (size_t)N * 4, stream);
    k_front     <<<AB + PACK_BLOCKS + DEG_BLOCKS, T, 0, stream>>>(
        feat, Ap1, W1, Bp1, W2, Bp2, dst, deg, N / 16 * 16 * 4 /*N*64/16? see below*/, E, AB);
    // NOTE: third-from-last arg is the idx bound = (N/16)*64 = N*4
    k_dinv_scan1<<<NB, T, 0, stream>>>(deg, dinv, bsum, N);
    k_scan2     <<<1, T, 0, stream>>>(bsum, NB, rowPtr, N);
    k_scan3     <<<NB, T, 0, stream>>>(deg, bsum, rowPtr, cursor, N);

    // layer-1 GEMM (packed A) fused with the independent edge scatter
    {
        int waves = (N + 15) / 16;                          // 6250
        int gemmBlocks = (waves * 64 + T - 1) / T;          // 1563
        int scatBlocks = (E + T - 1) / T;                   // 3125
        k_gemm_scatter<8, 8><<<gemmBlocks + scatBlocks, T, 0, stream>>>(
            Ap1, Bp1, XW1, N, gemmBlocks, src, dst, dinv, cursor, edata, E);
    }
    k_agg1<<<(N * 64 + T - 1) / T, T, 0, stream>>>(rowPtr, edata, XW1, dinv, b1, Hp, N);

    // layer 2: XW2 = bf16(Hp @ W2), A packed
    {
        int waves = (N + 15) / 16;
        k_gemm_p<4, 2><<<(waves * 64 + T - 1) / T, T, 0, stream>>>(Hp, Bp2, XW2, N);
    }
    k_agg2<<<(N * 64 + T - 1) / T, T, 0, stream>>>(rowPtr, edata, XW2, dinv, b2, out, N);
}

// Round 3
// 333.106 us; speedup vs baseline: 1.0617x; 1.0617x over previous
//
#include <hip/hip_runtime.h>
#include <hip/hip_bf16.h>

typedef __bf16 bf16_t;
typedef __attribute__((ext_vector_type(8))) __bf16 bf16x8;
typedef __attribute__((ext_vector_type(4))) float f32x4;

// ------- pack B[K,N] f32 -> bf16 MFMA fragments ---------------------------
__device__ inline void packB_one(const float* __restrict__ B, bf16_t* __restrict__ Bp,
                                 int N, int idx) {
    int j    = idx & 7;
    int lane = (idx >> 3) & 63;
    int st   = idx >> 9;
    int nt   = N >> 4;
    int s = st / nt, t = st - s * nt;
    int k = s * 32 + (lane >> 4) * 8 + j;
    int n = t * 16 + (lane & 15);
    Bp[idx] = (bf16_t)B[(size_t)k * N + n];
}

// ------- fused front-end: A-pack + weight pack + degree/rank count --------
// blocks [0, AB): feat f32 -> bf16 in MFMA fragment order
// blocks [AB, AB+144): weight packs
// blocks [AB+144, ...): deg histogram, 4 edges/thread; rank[e] = old count
//   (returning atomic: one fabric atomic per edge, the ONLY atomic pass)
__global__ __launch_bounds__(256) void k_front(
        const float* __restrict__ feat, bf16_t* __restrict__ Ap,
        const float* __restrict__ W1, bf16_t* __restrict__ Bp1,
        const float* __restrict__ W2, bf16_t* __restrict__ Bp2,
        const int* __restrict__ dst, int* __restrict__ deg,
        int* __restrict__ rank, int apThreads, int E, int AB) {
    int b = blockIdx.x, t = threadIdx.x;
    if (b < AB) {
        int idx = b * 256 + t;
        if (idx >= apThreads) return;          // apThreads = (N/16)*64
        int w    = idx >> 6;                   // 16-row strip
        int lane = idx & 63;
        int r16 = lane & 15, quad = lane >> 4;
        const float* arow = feat + (size_t)(w * 16 + r16) * 256 + quad * 8;
        bf16_t* opb = Ap + (size_t)w * 4096 + lane * 8;   // (w*8+s)*512 + lane*8
#pragma unroll
        for (int s = 0; s < 8; ++s) {
            const float* ap = arow + s * 32;
            bf16x8 a;
#pragma unroll
            for (int j = 0; j < 8; ++j) a[j] = (bf16_t)ap[j];
            *(bf16x8*)(opb + s * 512) = a;
        }
        return;
    }
    b -= AB;
    const int PACK_BLOCKS = (32768 + 4096) / 256;   // 144
    if (b < PACK_BLOCKS) {
        int idx = b * 256 + t;
        if (idx < 32768) packB_one(W1, Bp1, 128, idx);
        else             packB_one(W2, Bp2, 32, idx - 32768);
        return;
    }
    int i = (b - PACK_BLOCKS) * 1024 + t * 4;
    if (i + 4 <= E) {
        int4 v = *(const int4*)(dst + i);
        int4 r;
        r.x = atomicAdd(&deg[v.x], 1);
        r.y = atomicAdd(&deg[v.y], 1);
        r.z = atomicAdd(&deg[v.z], 1);
        r.w = atomicAdd(&deg[v.w], 1);
        *(int4*)(rank + i) = r;
    } else {
        for (int j = 0; j < 4; ++j)
            if (i + j < E) rank[i + j] = atomicAdd(&deg[dst[i + j]], 1);
    }
}

// ---------------- dinv + scan phase 1 (fused) -----------------------------
__global__ __launch_bounds__(256) void k_dinv_scan1(const int* __restrict__ deg,
                                                    float* __restrict__ dinv,
                                                    int* __restrict__ bsum, int n) {
    __shared__ int red[256];
    int b = blockIdx.x, t = threadIdx.x;
    int base = b * 1024 + t * 4;
    int s = 0;
#pragma unroll
    for (int j = 0; j < 4; ++j) {
        int i = base + j;
        if (i < n) { int d = deg[i]; s += d; dinv[i] = rsqrtf((float)(d + 1)); }
    }
    red[t] = s;
    __syncthreads();
    for (int d = 128; d > 0; d >>= 1) {
        if (t < d) red[t] += red[t + d];
        __syncthreads();
    }
    if (t == 0) bsum[b] = red[0];
}

// fused scan2+scan3: every block redundantly scans bsum (<=256 entries) in
// LDS for its own exclusive offset, then block-local scan -> rowPtr.
__global__ __launch_bounds__(256) void k_scan3f(const int* __restrict__ deg,
                                                const int* __restrict__ bsum, int nb,
                                                int* __restrict__ rowPtr, int n) {
    __shared__ int red[256];
    __shared__ int boff[256];
    int b = blockIdx.x, t = threadIdx.x;
    int base = b * 1024 + t * 4;
    int v[4]; int s = 0;
#pragma unroll
    for (int j = 0; j < 4; ++j) { int i = base + j; v[j] = (i < n) ? deg[i] : 0; s += v[j]; }
    red[t] = s;
    boff[t] = (t < nb) ? bsum[t] : 0;
    __syncthreads();
    for (int d = 1; d < 256; d <<= 1) {   // Hillis-Steele inclusive, both arrays
        int u  = (t >= d) ? red[t - d]  : 0;
        int u2 = (t >= d) ? boff[t - d] : 0;
        __syncthreads();
        red[t] += u;
        boff[t] += u2;
        __syncthreads();
    }
    int blockOff = (b == 0) ? 0 : boff[b - 1];          // exclusive block offset
    if (b == 0 && t == 0) rowPtr[n] = boff[nb - 1];     // total = E
    int run = blockOff + red[t] - s;
#pragma unroll
    for (int j = 0; j < 4; ++j) {
        int i = base + j;
        if (i < n) { rowPtr[i] = run; run += v[j]; }
    }
}

// ------- fused: packed-A GEMM + ATOMIC-FREE edge scatter ------------------
// scatter: edata[rowPtr[d] + rank[e]] = {src, nrm} -- no atomics, 4 edges/thr
template <int KSTEPS, int NTILES>
__global__ __launch_bounds__(256) void k_gemm_scatter(
        const bf16_t* __restrict__ Ap, const bf16_t* __restrict__ Bp,
        bf16_t* __restrict__ C, int M, int gemmBlocks,
        const int* __restrict__ src, const int* __restrict__ dst,
        const int* __restrict__ rank, const int* __restrict__ rowPtr,
        const float* __restrict__ dinv, int2* __restrict__ edata, int E) {
    int b = blockIdx.x, t = threadIdx.x;
    if (b < gemmBlocks) {
        int wave = (b * 256 + t) >> 6;
        if (wave * 16 >= M) return;
        int lane = t & 63;
        int r16 = lane & 15, quad = lane >> 4;
        const int N = NTILES * 16;
        f32x4 acc[NTILES] = {};
        const bf16_t* apb = Ap + (size_t)wave * (KSTEPS * 512) + lane * 8;
#pragma unroll
        for (int s = 0; s < KSTEPS; ++s) {
            bf16x8 a = *(const bf16x8*)(apb + s * 512);
            const bf16_t* bp = Bp + ((size_t)(s * NTILES) * 64 + lane) * 8;
#pragma unroll
            for (int tt = 0; tt < NTILES; ++tt) {
                bf16x8 bb = *(const bf16x8*)(bp + tt * 512);
                acc[tt] = __builtin_amdgcn_mfma_f32_16x16x32_bf16(a, bb, acc[tt], 0, 0, 0);
            }
        }
#pragma unroll
        for (int tt = 0; tt < NTILES; ++tt)
#pragma unroll
            for (int r = 0; r < 4; ++r)
                C[(size_t)(wave * 16 + quad * 4 + r) * N + tt * 16 + r16] = (bf16_t)acc[tt][r];
        return;
    }
    int i = (b - gemmBlocks) * 1024 + t * 4;
    if (i + 4 <= E) {
        int4 s4 = *(const int4*)(src + i);
        int4 d4 = *(const int4*)(dst + i);
        int4 r4 = *(const int4*)(rank + i);
        int p0 = rowPtr[d4.x] + r4.x, p1 = rowPtr[d4.y] + r4.y;
        int p2 = rowPtr[d4.z] + r4.z, p3 = rowPtr[d4.w] + r4.w;
        int2 e0; e0.x = s4.x; e0.y = __float_as_int(dinv[s4.x] * dinv[d4.x]);
        int2 e1; e1.x = s4.y; e1.y = __float_as_int(dinv[s4.y] * dinv[d4.y]);
        int2 e2; e2.x = s4.z; e2.y = __float_as_int(dinv[s4.z] * dinv[d4.z]);
        int2 e3; e3.x = s4.w; e3.y = __float_as_int(dinv[s4.w] * dinv[d4.w]);
        edata[p0] = e0; edata[p1] = e1; edata[p2] = e2; edata[p3] = e3;
    } else {
        for (int j = 0; j < 4; ++j) {
            int e = i + j;
            if (e >= E) break;
            int s = src[e], d = dst[e];
            int2 p; p.x = s; p.y = __float_as_int(dinv[s] * dinv[d]);
            edata[rowPtr[d] + rank[e]] = p;
        }
    }
}

// ------- packed-A GEMM (layer 2) ------------------------------------------
template <int KSTEPS, int NTILES>
__global__ __launch_bounds__(256) void k_gemm_p(
        const bf16_t* __restrict__ Ap, const bf16_t* __restrict__ Bp,
        bf16_t* __restrict__ C, int M) {
    int wave = (blockIdx.x * blockDim.x + threadIdx.x) >> 6;
    if (wave * 16 >= M) return;
    int lane = threadIdx.x & 63;
    int r16 = lane & 15, quad = lane >> 4;
    const int N = NTILES * 16;
    f32x4 acc[NTILES] = {};
    const bf16_t* apb = Ap + (size_t)wave * (KSTEPS * 512) + lane * 8;
#pragma unroll
    for (int s = 0; s < KSTEPS; ++s) {
        bf16x8 a = *(const bf16x8*)(apb + s * 512);
        const bf16_t* bp = Bp + ((size_t)(s * NTILES) * 64 + lane) * 8;
#pragma unroll
        for (int t = 0; t < NTILES; ++t) {
            bf16x8 b = *(const bf16x8*)(bp + t * 512);
            acc[t] = __builtin_amdgcn_mfma_f32_16x16x32_bf16(a, b, acc[t], 0, 0, 0);
        }
    }
#pragma unroll
    for (int t = 0; t < NTILES; ++t)
#pragma unroll
        for (int r = 0; r < 4; ++r)
            C[(size_t)(wave * 16 + quad * 4 + r) * N + t * 16 + r16] = (bf16_t)acc[t][r];
}

// ------- layer-1 aggregate: writes H directly in packed fragment layout ---
__global__ __launch_bounds__(256) void k_agg1(
        const int* __restrict__ rowPtr, const int2* __restrict__ edata,
        const bf16_t* __restrict__ XW1, const float* __restrict__ dinv,
        const float* __restrict__ b1, bf16_t* __restrict__ Hp, int n) {
    int wave = (blockIdx.x * blockDim.x + threadIdx.x) >> 6;
    if (wave >= n) return;
    int lane = threadIdx.x & 63;
    int fl = (lane & 15) << 3;   // 8 features
    int h  = lane >> 4;          // parity stream 0..3
    int r0 = rowPtr[wave], r1 = rowPtr[wave + 1];
    float a0[8] = {}, a1[8] = {};
    int k = r0 + h;
    for (; k + 4 < r1; k += 8) {          // 2 independent gathers in flight
        int2 e0 = edata[k], e1 = edata[k + 4];
        float w0 = __int_as_float(e0.y), w1 = __int_as_float(e1.y);
        bf16x8 x0 = *(const bf16x8*)(XW1 + ((size_t)e0.x << 7) + fl);
        bf16x8 x1 = *(const bf16x8*)(XW1 + ((size_t)e1.x << 7) + fl);
#pragma unroll
        for (int j = 0; j < 8; ++j) { a0[j] += (float)x0[j] * w0; a1[j] += (float)x1[j] * w1; }
    }
    if (k < r1) {
        int2 e0 = edata[k];
        float w0 = __int_as_float(e0.y);
        bf16x8 x0 = *(const bf16x8*)(XW1 + ((size_t)e0.x << 7) + fl);
#pragma unroll
        for (int j = 0; j < 8; ++j) a0[j] += (float)x0[j] * w0;
    }
#pragma unroll
    for (int j = 0; j < 8; ++j) {        // convergent reduction over 4 streams
        a0[j] += a1[j];
        a0[j] += __shfl_xor(a0[j], 16);
        a0[j] += __shfl_xor(a0[j], 32);
    }
    if (h == 0) {
        float d = dinv[wave], d2 = d * d;
        bf16x8 xs = *(const bf16x8*)(XW1 + ((size_t)wave << 7) + fl);
        bf16x8 hv;
#pragma unroll
        for (int j = 0; j < 8; ++j) {
            float v = a0[j] + (float)xs[j] * d2 + b1[fl + j];
            hv[j] = (bf16_t)fmaxf(v, 0.f);
        }
        int q = lane & 15;
        size_t off = (((size_t)(wave >> 4) * 4 + (q >> 2)) * 64
                      + (wave & 15) + 16 * (q & 3)) * 8;
        *(bf16x8*)(Hp + off) = hv;
    }
}

// ------- layer-2 aggregate + log_softmax ----------------------------------
__global__ __launch_bounds__(256) void k_agg2(
        const int* __restrict__ rowPtr, const int2* __restrict__ edata,
        const bf16_t* __restrict__ XW2, const float* __restrict__ dinv,
        const float* __restrict__ b2, float* __restrict__ out, int n) {
    int wave = (blockIdx.x * blockDim.x + threadIdx.x) >> 6;
    if (wave >= n) return;
    int lane = threadIdx.x & 63;
    int g = lane & 15;           // class pair: {2g, 2g+1}
    int h = lane >> 4;           // stream 0..3
    int r0 = rowPtr[wave], r1 = rowPtr[wave + 1];
    float a00 = 0.f, a01 = 0.f, a10 = 0.f, a11 = 0.f;
    int k = r0 + h;
    for (; k + 4 < r1; k += 8) {
        int2 e0 = edata[k], e1 = edata[k + 4];
        float w0 = __int_as_float(e0.y), w1 = __int_as_float(e1.y);
        unsigned p0 = *(const unsigned*)(XW2 + ((size_t)e0.x << 5) + 2 * g);
        unsigned p1 = *(const unsigned*)(XW2 + ((size_t)e1.x << 5) + 2 * g);
        a00 += __int_as_float(p0 << 16) * w0;
        a01 += __int_as_float(p0 & 0xffff0000u) * w0;
        a10 += __int_as_float(p1 << 16) * w1;
        a11 += __int_as_float(p1 & 0xffff0000u) * w1;
    }
    if (k < r1) {
        int2 e0 = edata[k];
        float w0 = __int_as_float(e0.y);
        unsigned p0 = *(const unsigned*)(XW2 + ((size_t)e0.x << 5) + 2 * g);
        a00 += __int_as_float(p0 << 16) * w0;
        a01 += __int_as_float(p0 & 0xffff0000u) * w0;
    }
    float v0 = a00 + a10, v1 = a01 + a11;
    v0 += __shfl_xor(v0, 16); v0 += __shfl_xor(v0, 32);   // combine 4 streams
    v1 += __shfl_xor(v1, 16); v1 += __shfl_xor(v1, 32);
    float d = dinv[wave], d2 = d * d;
    unsigned ps = *(const unsigned*)(XW2 + ((size_t)wave << 5) + 2 * g);
    float2 bb = *(const float2*)(b2 + 2 * g);
    v0 += __int_as_float(ps << 16) * d2 + bb.x;
    v1 += __int_as_float(ps & 0xffff0000u) * d2 + bb.y;
    float mx = fmaxf(v0, v1);
#pragma unroll
    for (int m = 8; m >= 1; m >>= 1) mx = fmaxf(mx, __shfl_xor(mx, m));
    float s = expf(v0 - mx) + expf(v1 - mx);
#pragma unroll
    for (int m = 8; m >= 1; m >>= 1) s += __shfl_xor(s, m);
    if (h == 0) {
        float ls = logf(s);
        float2 o; o.x = v0 - mx - ls; o.y = v1 - mx - ls;
        *(float2*)(out + ((size_t)wave << 5) + 2 * g) = o;
    }
}

extern "C" void kernel_launch(void* const* d_in, const int* in_sizes, int n_in,
                              void* d_out, int out_size, void* d_ws, size_t ws_size,
                              hipStream_t stream) {
    const float* feat = (const float*)d_in[0];
    const int*   eidx = (const int*)d_in[1];
    const float* W1   = (const float*)d_in[2];
    const float* b1   = (const float*)d_in[3];
    const float* W2   = (const float*)d_in[4];
    const float* b2   = (const float*)d_in[5];
    float* out = (float*)d_out;

    const int FIN = 256, HID = 128, NCLS = 32;
    const int N = in_sizes[0] / FIN;   // 100000
    const int E = in_sizes[1] / 2;     // 800000
    const int* src = eidx;
    const int* dst = eidx + E;

    // workspace carve-up (256B aligned)
    char* ws = (char*)d_ws;
    size_t o = 0;
    auto alloc = [&](size_t bytes) -> void* {
        void* p = ws + o;
        o = (o + bytes + 255) & ~(size_t)255;
        return p;
    };
    int*    deg    = (int*)   alloc((size_t)N * 4);
    int*    rank   = (int*)   alloc((size_t)E * 4);         // 3.2 MB edge ranks
    float*  dinv   = (float*) alloc((size_t)N * 4);
    int*    rowPtr = (int*)   alloc((size_t)(N + 1) * 4);
    int*    bsum   = (int*)   alloc(256 * 4);
    bf16_t* Bp1    = (bf16_t*)alloc((size_t)(FIN / 32) * (HID / 16) * 512 * 2);
    bf16_t* Bp2    = (bf16_t*)alloc((size_t)(HID / 32) * (NCLS / 16) * 512 * 2);
    int2*   edata  = (int2*)  alloc((size_t)E * 8);         // 6.4 MB
    bf16_t* Ap1    = (bf16_t*)alloc((size_t)N * FIN * 2);   // 51.2 MB packed feat
    bf16_t* XW1    = (bf16_t*)alloc((size_t)N * HID * 2);   // 25.6 MB
    bf16_t* Hp     = (bf16_t*)alloc((size_t)N * HID * 2);   // 25.6 MB packed H
    bf16_t* XW2    = XW1;   // alias: XW1 dead after k_agg1

    const int T = 256;
    const int NB = (N + 1023) >> 10;                 // 98 scan blocks (<=256)
    const int apThreads = (N / 16) * 64;             // 400000
    const int AB = (apThreads + T - 1) / T;          // 1563
    const int PACK_BLOCKS = (32768 + 4096) / 256;    // 144
    const int DEG_BLOCKS  = (E + 1023) / 1024;       // 782 (4 edges/thread)
    hipMemsetAsync(deg, 0, (size_t)N * 4, stream);
    k_front<<<AB + PACK_BLOCKS + DEG_BLOCKS, T, 0, stream>>>(
        feat, Ap1, W1, Bp1, W2, Bp2, dst, deg, rank, apThreads, E, AB);
    k_dinv_scan1<<<NB, T, 0, stream>>>(deg, dinv, bsum, N);
    k_scan3f    <<<NB, T, 0, stream>>>(deg, bsum, NB, rowPtr, N);

    // layer-1 GEMM (packed A) fused with the atomic-free edge scatter
    {
        int waves = (N + 15) / 16;                          // 6250
        int gemmBlocks = (waves * 64 + T - 1) / T;          // 1563
        int scatBlocks = (E + 1023) / 1024;                 // 782 (4 edges/thread)
        k_gemm_scatter<8, 8><<<gemmBlocks + scatBlocks, T, 0, stream>>>(
            Ap1, Bp1, XW1, N, gemmBlocks, src, dst, rank, rowPtr, dinv, edata, E);
    }
    k_agg1<<<(N * 64 + T - 1) / T, T, 0, stream>>>(rowPtr, edata, XW1, dinv, b1, Hp, N);

    // layer 2: XW2 = bf16(Hp @ W2), A packed
    {
        int waves = (N + 15) / 16;
        k_gemm_p<4, 2><<<(waves * 64 + T - 1) / T, T, 0, stream>>>(Hp, Bp2, XW2, N);
    }
    k_agg2<<<(N * 64 + T - 1) / T, T, 0, stream>>>(rowPtr, edata, XW2, dinv, b2, out, N);
}

// Round 4
// 325.449 us; speedup vs baseline: 1.0867x; 1.0235x over previous
//
#include <hip/hip_runtime.h>
#include <hip/hip_bf16.h>

typedef __bf16 bf16_t;
typedef __attribute__((ext_vector_type(8))) __bf16 bf16x8;
typedef __attribute__((ext_vector_type(4))) float f32x4;

// ------- pack B[K,N] f32 -> bf16 MFMA fragments ---------------------------
__device__ inline void packB_one(const float* __restrict__ B, bf16_t* __restrict__ Bp,
                                 int N, int idx) {
    int j    = idx & 7;
    int lane = (idx >> 3) & 63;
    int st   = idx >> 9;
    int nt   = N >> 4;
    int s = st / nt, t = st - s * nt;
    int k = s * 32 + (lane >> 4) * 8 + j;
    int n = t * 16 + (lane & 15);
    Bp[idx] = (bf16_t)B[(size_t)k * N + n];
}

// ------- fused front-end: deg/rank atomics ∥ f32-A GEMM1 ∥ weight packs ---
// The 800k random fabric atomics are a ~75us latency wall that uses neither
// the VMEM-load queue nor MFMA; the f32-A GEMM (latency-bound on feat reads)
// coexists with it (R1 evidence: 87us = max, not sum). All three phases are
// mutually independent.
// blocks [0, DEGB):        deg histogram + rank[e] = returned old count
// blocks [DEGB, +GEMMB):   XW1 = bf16(feat @ W1), MFMA 16x16x32, f32 A loads
// blocks [DEGB+GEMMB, +144): pack W1,W2 fragments
template <int KSTEPS, int NTILES>
__global__ __launch_bounds__(256) void k_front(
        const float* __restrict__ feat, const bf16_t* __restrict__ Bp1r,
        bf16_t* __restrict__ XW1, int M,
        const float* __restrict__ W1, bf16_t* __restrict__ Bp1,
        const float* __restrict__ W2, bf16_t* __restrict__ Bp2,
        const int* __restrict__ dst, int* __restrict__ deg,
        int* __restrict__ rank, int E, int DEGB, int GEMMB) {
    int b = blockIdx.x, t = threadIdx.x;
    if (b < DEGB) {
        int i = b * 1024 + t * 4;
        if (i + 4 <= E) {
            int4 v = *(const int4*)(dst + i);
            int4 r;
            r.x = atomicAdd(&deg[v.x], 1);
            r.y = atomicAdd(&deg[v.y], 1);
            r.z = atomicAdd(&deg[v.z], 1);
            r.w = atomicAdd(&deg[v.w], 1);
            *(int4*)(rank + i) = r;
        } else {
            for (int j = 0; j < 4; ++j)
                if (i + j < E) rank[i + j] = atomicAdd(&deg[dst[i + j]], 1);
        }
        return;
    }
    b -= DEGB;
    if (b < GEMMB) {
        int wave = (b * 256 + t) >> 6;
        if (wave * 16 >= M) return;
        int lane = t & 63;
        int r16 = lane & 15, quad = lane >> 4;
        const int K = KSTEPS * 32, N = NTILES * 16;
        f32x4 acc[NTILES] = {};
        const float* arow = feat + (size_t)(wave * 16 + r16) * K + quad * 8;
#pragma unroll
        for (int s = 0; s < KSTEPS; ++s) {
            const float* ap = arow + s * 32;
            bf16x8 a;
#pragma unroll
            for (int j = 0; j < 8; ++j) a[j] = (bf16_t)ap[j];
            const bf16_t* bp = Bp1r + ((size_t)(s * NTILES) * 64 + lane) * 8;
#pragma unroll
            for (int tt = 0; tt < NTILES; ++tt) {
                bf16x8 bb = *(const bf16x8*)(bp + tt * 512);
                acc[tt] = __builtin_amdgcn_mfma_f32_16x16x32_bf16(a, bb, acc[tt], 0, 0, 0);
            }
        }
#pragma unroll
        for (int tt = 0; tt < NTILES; ++tt)
#pragma unroll
            for (int r = 0; r < 4; ++r)
                XW1[(size_t)(wave * 16 + quad * 4 + r) * N + tt * 16 + r16] = (bf16_t)acc[tt][r];
        return;
    }
    b -= GEMMB;
    int idx = b * 256 + t;
    if (idx < 32768) packB_one(W1, Bp1, 128, idx);
    else             packB_one(W2, Bp2, 32, idx - 32768);
}

// ---------------- dinv + scan phase 1 (fused) -----------------------------
__global__ __launch_bounds__(256) void k_dinv_scan1(const int* __restrict__ deg,
                                                    float* __restrict__ dinv,
                                                    int* __restrict__ bsum, int n) {
    __shared__ int red[256];
    int b = blockIdx.x, t = threadIdx.x;
    int base = b * 1024 + t * 4;
    int s = 0;
#pragma unroll
    for (int j = 0; j < 4; ++j) {
        int i = base + j;
        if (i < n) { int d = deg[i]; s += d; dinv[i] = rsqrtf((float)(d + 1)); }
    }
    red[t] = s;
    __syncthreads();
    for (int d = 128; d > 0; d >>= 1) {
        if (t < d) red[t] += red[t + d];
        __syncthreads();
    }
    if (t == 0) bsum[b] = red[0];
}

// fused scan2+scan3: every block redundantly scans bsum (<=256 entries) in
// LDS for its own exclusive offset, then block-local scan -> rowPtr.
__global__ __launch_bounds__(256) void k_scan3f(const int* __restrict__ deg,
                                                const int* __restrict__ bsum, int nb,
                                                int* __restrict__ rowPtr, int n) {
    __shared__ int red[256];
    __shared__ int boff[256];
    int b = blockIdx.x, t = threadIdx.x;
    int base = b * 1024 + t * 4;
    int v[4]; int s = 0;
#pragma unroll
    for (int j = 0; j < 4; ++j) { int i = base + j; v[j] = (i < n) ? deg[i] : 0; s += v[j]; }
    red[t] = s;
    boff[t] = (t < nb) ? bsum[t] : 0;
    __syncthreads();
    for (int d = 1; d < 256; d <<= 1) {   // Hillis-Steele inclusive, both arrays
        int u  = (t >= d) ? red[t - d]  : 0;
        int u2 = (t >= d) ? boff[t - d] : 0;
        __syncthreads();
        red[t] += u;
        boff[t] += u2;
        __syncthreads();
    }
    int blockOff = (b == 0) ? 0 : boff[b - 1];          // exclusive block offset
    if (b == 0 && t == 0) rowPtr[n] = boff[nb - 1];     // total = E
    int run = blockOff + red[t] - s;
#pragma unroll
    for (int j = 0; j < 4; ++j) {
        int i = base + j;
        if (i < n) { rowPtr[i] = run; run += v[j]; }
    }
}

// ------- atomic-free edge scatter: edata[rowPtr[d]+rank[e]] = {src,nrm} ---
__global__ __launch_bounds__(256) void k_scatter(
        const int* __restrict__ src, const int* __restrict__ dst,
        const int* __restrict__ rank, const int* __restrict__ rowPtr,
        const float* __restrict__ dinv, int2* __restrict__ edata, int E) {
    int i = (blockIdx.x * 256 + threadIdx.x) * 4;
    if (i + 4 <= E) {
        int4 s4 = *(const int4*)(src + i);
        int4 d4 = *(const int4*)(dst + i);
        int4 r4 = *(const int4*)(rank + i);
        int p0 = rowPtr[d4.x] + r4.x, p1 = rowPtr[d4.y] + r4.y;
        int p2 = rowPtr[d4.z] + r4.z, p3 = rowPtr[d4.w] + r4.w;
        int2 e0; e0.x = s4.x; e0.y = __float_as_int(dinv[s4.x] * dinv[d4.x]);
        int2 e1; e1.x = s4.y; e1.y = __float_as_int(dinv[s4.y] * dinv[d4.y]);
        int2 e2; e2.x = s4.z; e2.y = __float_as_int(dinv[s4.z] * dinv[d4.z]);
        int2 e3; e3.x = s4.w; e3.y = __float_as_int(dinv[s4.w] * dinv[d4.w]);
        edata[p0] = e0; edata[p1] = e1; edata[p2] = e2; edata[p3] = e3;
    } else {
        for (int j = 0; j < 4; ++j) {
            int e = i + j;
            if (e >= E) break;
            int s = src[e], d = dst[e];
            int2 p; p.x = s; p.y = __float_as_int(dinv[s] * dinv[d]);
            edata[rowPtr[d] + rank[e]] = p;
        }
    }
}

// ------- packed-A GEMM (layer 2) ------------------------------------------
template <int KSTEPS, int NTILES>
__global__ __launch_bounds__(256) void k_gemm_p(
        const bf16_t* __restrict__ Ap, const bf16_t* __restrict__ Bp,
        bf16_t* __restrict__ C, int M) {
    int wave = (blockIdx.x * blockDim.x + threadIdx.x) >> 6;
    if (wave * 16 >= M) return;
    int lane = threadIdx.x & 63;
    int r16 = lane & 15, quad = lane >> 4;
    const int N = NTILES * 16;
    f32x4 acc[NTILES] = {};
    const bf16_t* apb = Ap + (size_t)wave * (KSTEPS * 512) + lane * 8;
#pragma unroll
    for (int s = 0; s < KSTEPS; ++s) {
        bf16x8 a = *(const bf16x8*)(apb + s * 512);
        const bf16_t* bp = Bp + ((size_t)(s * NTILES) * 64 + lane) * 8;
#pragma unroll
        for (int t = 0; t < NTILES; ++t) {
            bf16x8 b = *(const bf16x8*)(bp + t * 512);
            acc[t] = __builtin_amdgcn_mfma_f32_16x16x32_bf16(a, b, acc[t], 0, 0, 0);
        }
    }
#pragma unroll
    for (int t = 0; t < NTILES; ++t)
#pragma unroll
        for (int r = 0; r < 4; ++r)
            C[(size_t)(wave * 16 + quad * 4 + r) * N + t * 16 + r16] = (bf16_t)acc[t][r];
}

// ------- layer-1 aggregate: writes H directly in packed fragment layout ---
__global__ __launch_bounds__(256) void k_agg1(
        const int* __restrict__ rowPtr, const int2* __restrict__ edata,
        const bf16_t* __restrict__ XW1, const float* __restrict__ dinv,
        const float* __restrict__ b1, bf16_t* __restrict__ Hp, int n) {
    int wave = (blockIdx.x * blockDim.x + threadIdx.x) >> 6;
    if (wave >= n) return;
    int lane = threadIdx.x & 63;
    int fl = (lane & 15) << 3;   // 8 features
    int h  = lane >> 4;          // parity stream 0..3
    int r0 = rowPtr[wave], r1 = rowPtr[wave + 1];
    // self-term preload (independent, hides under the gather loop)
    float d = dinv[wave], d2 = d * d;
    bf16x8 xs = *(const bf16x8*)(XW1 + ((size_t)wave << 7) + fl);
    float a0[8] = {}, a1[8] = {};
    int k = r0 + h;
    for (; k + 4 < r1; k += 8) {          // 2 independent gathers in flight
        int2 e0 = edata[k], e1 = edata[k + 4];
        float w0 = __int_as_float(e0.y), w1 = __int_as_float(e1.y);
        bf16x8 x0 = *(const bf16x8*)(XW1 + ((size_t)e0.x << 7) + fl);
        bf16x8 x1 = *(const bf16x8*)(XW1 + ((size_t)e1.x << 7) + fl);
#pragma unroll
        for (int j = 0; j < 8; ++j) { a0[j] += (float)x0[j] * w0; a1[j] += (float)x1[j] * w1; }
    }
    if (k < r1) {
        int2 e0 = edata[k];
        float w0 = __int_as_float(e0.y);
        bf16x8 x0 = *(const bf16x8*)(XW1 + ((size_t)e0.x << 7) + fl);
#pragma unroll
        for (int j = 0; j < 8; ++j) a0[j] += (float)x0[j] * w0;
    }
#pragma unroll
    for (int j = 0; j < 8; ++j) {        // convergent reduction over 4 streams
        a0[j] += a1[j];
        a0[j] += __shfl_xor(a0[j], 16);
        a0[j] += __shfl_xor(a0[j], 32);
    }
    if (h == 0) {
        bf16x8 hv;
#pragma unroll
        for (int j = 0; j < 8; ++j) {
            float v = a0[j] + (float)xs[j] * d2 + b1[fl + j];
            hv[j] = (bf16_t)fmaxf(v, 0.f);
        }
        int q = lane & 15;
        size_t off = (((size_t)(wave >> 4) * 4 + (q >> 2)) * 64
                      + (wave & 15) + 16 * (q & 3)) * 8;
        *(bf16x8*)(Hp + off) = hv;
    }
}

// ------- layer-2 aggregate + log_softmax ----------------------------------
__global__ __launch_bounds__(256) void k_agg2(
        const int* __restrict__ rowPtr, const int2* __restrict__ edata,
        const bf16_t* __restrict__ XW2, const float* __restrict__ dinv,
        const float* __restrict__ b2, float* __restrict__ out, int n) {
    int wave = (blockIdx.x * blockDim.x + threadIdx.x) >> 6;
    if (wave >= n) return;
    int lane = threadIdx.x & 63;
    int g = lane & 15;           // class pair: {2g, 2g+1}
    int h = lane >> 4;           // stream 0..3
    int r0 = rowPtr[wave], r1 = rowPtr[wave + 1];
    // self-term preload
    float d = dinv[wave], d2 = d * d;
    unsigned ps = *(const unsigned*)(XW2 + ((size_t)wave << 5) + 2 * g);
    float2 bb = *(const float2*)(b2 + 2 * g);
    float a00 = 0.f, a01 = 0.f, a10 = 0.f, a11 = 0.f;
    int k = r0 + h;
    for (; k + 4 < r1; k += 8) {
        int2 e0 = edata[k], e1 = edata[k + 4];
        float w0 = __int_as_float(e0.y), w1 = __int_as_float(e1.y);
        unsigned p0 = *(const unsigned*)(XW2 + ((size_t)e0.x << 5) + 2 * g);
        unsigned p1 = *(const unsigned*)(XW2 + ((size_t)e1.x << 5) + 2 * g);
        a00 += __int_as_float(p0 << 16) * w0;
        a01 += __int_as_float(p0 & 0xffff0000u) * w0;
        a10 += __int_as_float(p1 << 16) * w1;
        a11 += __int_as_float(p1 & 0xffff0000u) * w1;
    }
    if (k < r1) {
        int2 e0 = edata[k];
        float w0 = __int_as_float(e0.y);
        unsigned p0 = *(const unsigned*)(XW2 + ((size_t)e0.x << 5) + 2 * g);
        a00 += __int_as_float(p0 << 16) * w0;
        a01 += __int_as_float(p0 & 0xffff0000u) * w0;
    }
    float v0 = a00 + a10, v1 = a01 + a11;
    v0 += __shfl_xor(v0, 16); v0 += __shfl_xor(v0, 32);   // combine 4 streams
    v1 += __shfl_xor(v1, 16); v1 += __shfl_xor(v1, 32);
    v0 += __int_as_float(ps << 16) * d2 + bb.x;
    v1 += __int_as_float(ps & 0xffff0000u) * d2 + bb.y;
    float mx = fmaxf(v0, v1);
#pragma unroll
    for (int m = 8; m >= 1; m >>= 1) mx = fmaxf(mx, __shfl_xor(mx, m));
    float s = __expf(v0 - mx) + __expf(v1 - mx);
#pragma unroll
    for (int m = 8; m >= 1; m >>= 1) s += __shfl_xor(s, m);
    if (h == 0) {
        float ls = __logf(s);
        float2 o; o.x = v0 - mx - ls; o.y = v1 - mx - ls;
        *(float2*)(out + ((size_t)wave << 5) + 2 * g) = o;
    }
}

extern "C" void kernel_launch(void* const* d_in, const int* in_sizes, int n_in,
                              void* d_out, int out_size, void* d_ws, size_t ws_size,
                              hipStream_t stream) {
    const float* feat = (const float*)d_in[0];
    const int*   eidx = (const int*)d_in[1];
    const float* W1   = (const float*)d_in[2];
    const float* b1   = (const float*)d_in[3];
    const float* W2   = (const float*)d_in[4];
    const float* b2   = (const float*)d_in[5];
    float* out = (float*)d_out;

    const int FIN = 256, HID = 128, NCLS = 32;
    const int N = in_sizes[0] / FIN;   // 100000
    const int E = in_sizes[1] / 2;     // 800000
    const int* src = eidx;
    const int* dst = eidx + E;

    // workspace carve-up (256B aligned)
    char* ws = (char*)d_ws;
    size_t o = 0;
    auto alloc = [&](size_t bytes) -> void* {
        void* p = ws + o;
        o = (o + bytes + 255) & ~(size_t)255;
        return p;
    };
    int*    deg    = (int*)   alloc((size_t)N * 4);
    int*    rank   = (int*)   alloc((size_t)E * 4);         // 3.2 MB edge ranks
    float*  dinv   = (float*) alloc((size_t)N * 4);
    int*    rowPtr = (int*)   alloc((size_t)(N + 1) * 4);
    int*    bsum   = (int*)   alloc(256 * 4);
    bf16_t* Bp1    = (bf16_t*)alloc((size_t)(FIN / 32) * (HID / 16) * 512 * 2);
    bf16_t* Bp2    = (bf16_t*)alloc((size_t)(HID / 32) * (NCLS / 16) * 512 * 2);
    int2*   edata  = (int2*)  alloc((size_t)E * 8);         // 6.4 MB
    bf16_t* XW1    = (bf16_t*)alloc((size_t)N * HID * 2);   // 25.6 MB
    bf16_t* Hp     = (bf16_t*)alloc((size_t)N * HID * 2);   // 25.6 MB packed H
    bf16_t* XW2    = XW1;   // alias: XW1 dead after k_agg1

    const int T = 256;
    const int NB = (N + 1023) >> 10;                 // 98 scan blocks (<=256)
    const int DEGB  = (E + 1023) / 1024;             // 782 (4 edges/thread)
    const int GEMMB = (((N + 15) / 16) * 64 + T - 1) / T;   // 1563
    const int PACKB = (32768 + 4096) / 256;          // 144
    hipMemsetAsync(deg, 0, (size_t)N * 4, stream);
    // NOTE: XW1 here is written by the GEMM phase; Bp1 is both written by the
    // pack phase and read by the GEMM phase -- but NOT in the same launch:
    // the GEMM phase reads Bp1r which must be ready. Bp1 is packed in THIS
    // kernel, so the GEMM must not depend on it... it does. Resolution: the
    // weights are tiny (132 KB); pack them FIRST in a micro-kernel so the
    // fused front's GEMM phase has Bp1 ready.
    // (packing is 2 us; it cannot hide anything anyway)
    {
        // tiny pack-only launch: 144 blocks
        // reuse k_front's pack branch via DEGB=0, GEMMB=0
        k_front<8, 8><<<PACKB, T, 0, stream>>>(
            feat, Bp1, XW1, 0, W1, Bp1, W2, Bp2, dst, deg, rank, 0, 0, 0);
    }
    k_front<8, 8><<<DEGB + GEMMB, T, 0, stream>>>(
        feat, Bp1, XW1, N, W1, Bp1, W2, Bp2, dst, deg, rank, E, DEGB, GEMMB);
    k_dinv_scan1<<<NB, T, 0, stream>>>(deg, dinv, bsum, N);
    k_scan3f    <<<NB, T, 0, stream>>>(deg, bsum, NB, rowPtr, N);
    k_scatter   <<<(E + 1023) / 1024, T, 0, stream>>>(src, dst, rank, rowPtr, dinv, edata, E);
    k_agg1<<<(N * 64 + T - 1) / T, T, 0, stream>>>(rowPtr, edata, XW1, dinv, b1, Hp, N);
    // layer 2: XW2 = bf16(Hp @ W2), A packed
    {
        int waves = (N + 15) / 16;
        k_gemm_p<4, 2><<<(waves * 64 + T - 1) / T, T, 0, stream>>>(Hp, Bp2, XW2, N);
    }
    k_agg2<<<(N * 64 + T - 1) / T, T, 0, stream>>>(rowPtr, edata, XW2, dinv, b2, out, N);
}

// Round 5
// 317.780 us; speedup vs baseline: 1.1129x; 1.0241x over previous
//
#include <hip/hip_runtime.h>
#include <hip/hip_bf16.h>

typedef __bf16 bf16_t;
typedef __attribute__((ext_vector_type(8))) __bf16 bf16x8;
typedef __attribute__((ext_vector_type(4))) float f32x4;
typedef __attribute__((ext_vector_type(2))) float f32x2;

// ------- pack B[K,N] f32 -> bf16 MFMA fragments ---------------------------
__device__ inline void packB_one(const float* __restrict__ B, bf16_t* __restrict__ Bp,
                                 int N, int idx) {
    int j    = idx & 7;
    int lane = (idx >> 3) & 63;
    int st   = idx >> 9;
    int nt   = N >> 4;
    int s = st / nt, t = st - s * nt;
    int k = s * 32 + (lane >> 4) * 8 + j;
    int n = t * 16 + (lane & 15);
    Bp[idx] = (bf16_t)B[(size_t)k * N + n];
}

// fp8 e4m3 decode: 8 fp8 (uint2) -> fma into a[0..8) with weight w
__device__ inline void fma8_fp8(uint2 u, float w, float* a) {
    f32x2 p;
    p = __builtin_amdgcn_cvt_pk_f32_fp8(u.x, false); a[0] += p[0] * w; a[1] += p[1] * w;
    p = __builtin_amdgcn_cvt_pk_f32_fp8(u.x, true);  a[2] += p[0] * w; a[3] += p[1] * w;
    p = __builtin_amdgcn_cvt_pk_f32_fp8(u.y, false); a[4] += p[0] * w; a[5] += p[1] * w;
    p = __builtin_amdgcn_cvt_pk_f32_fp8(u.y, true);  a[6] += p[0] * w; a[7] += p[1] * w;
}

// ------- prep: pack W1/W2 fragments + zero deg (replaces memset) ----------
__global__ __launch_bounds__(256) void k_prep(
        const float* __restrict__ W1, bf16_t* __restrict__ Bp1,
        const float* __restrict__ W2, bf16_t* __restrict__ Bp2,
        int* __restrict__ deg, int N) {
    int b = blockIdx.x, t = threadIdx.x;
    const int PACKB = (32768 + 4096) / 256;   // 144
    if (b < PACKB) {
        int idx = b * 256 + t;
        if (idx < 32768) packB_one(W1, Bp1, 128, idx);
        else             packB_one(W2, Bp2, 32, idx - 32768);
        return;
    }
    int i = ((b - PACKB) * 256 + t) * 4;
    if (i < N) {
        if (i + 4 <= N) *(int4*)(deg + i) = make_int4(0, 0, 0, 0);
        else for (int j = 0; i + j < N; ++j) deg[i + j] = 0;
    }
}

// ------- fused front-end: deg/rank atomic wall ∥ f32-A GEMM1 (fp8 out) ----
// The 800k random fabric atomics are a ~75us latency wall using neither the
// VMEM-load queue nor MFMA; the f32-A GEMM coexists with it (R1/R4 evidence).
// blocks [0, DEGB):      deg histogram + rank[e] = returned old count
// blocks [DEGB, +GEMMB): XW1 = fp8_e4m3(feat @ W1), MFMA 16x16x32
template <int KSTEPS, int NTILES>
__global__ __launch_bounds__(256) void k_front(
        const float* __restrict__ feat, const bf16_t* __restrict__ Bp1,
        unsigned char* __restrict__ XW1, int M,
        const int* __restrict__ dst, int* __restrict__ deg,
        int* __restrict__ rank, int E, int DEGB) {
    int b = blockIdx.x, t = threadIdx.x;
    if (b < DEGB) {
        int i = b * 1024 + t * 4;
        if (i + 4 <= E) {
            int4 v = *(const int4*)(dst + i);
            int4 r;
            r.x = atomicAdd(&deg[v.x], 1);
            r.y = atomicAdd(&deg[v.y], 1);
            r.z = atomicAdd(&deg[v.z], 1);
            r.w = atomicAdd(&deg[v.w], 1);
            *(int4*)(rank + i) = r;
        } else {
            for (int j = 0; j < 4; ++j)
                if (i + j < E) rank[i + j] = atomicAdd(&deg[dst[i + j]], 1);
        }
        return;
    }
    b -= DEGB;
    {
        int wave = (b * 256 + t) >> 6;
        if (wave * 16 >= M) return;
        int lane = t & 63;
        int r16 = lane & 15, quad = lane >> 4;
        const int K = KSTEPS * 32, N = NTILES * 16;
        f32x4 acc[NTILES] = {};
        const float* arow = feat + (size_t)(wave * 16 + r16) * K + quad * 8;
#pragma unroll
        for (int s = 0; s < KSTEPS; ++s) {
            const float* ap = arow + s * 32;
            bf16x8 a;
#pragma unroll
            for (int j = 0; j < 8; ++j) a[j] = (bf16_t)ap[j];
            const bf16_t* bp = Bp1 + ((size_t)(s * NTILES) * 64 + lane) * 8;
#pragma unroll
            for (int tt = 0; tt < NTILES; ++tt) {
                bf16x8 bb = *(const bf16x8*)(bp + tt * 512);
                acc[tt] = __builtin_amdgcn_mfma_f32_16x16x32_bf16(a, bb, acc[tt], 0, 0, 0);
            }
        }
#pragma unroll
        for (int tt = 0; tt < NTILES; ++tt)
#pragma unroll
            for (int r = 0; r < 4; ++r) {
                int pk = __builtin_amdgcn_cvt_pk_fp8_f32(acc[tt][r], acc[tt][r], 0, false);
                XW1[(size_t)(wave * 16 + quad * 4 + r) * N + tt * 16 + r16] =
                    (unsigned char)pk;
            }
    }
}

// ---------------- dinv + scan phase 1 (fused) -----------------------------
__global__ __launch_bounds__(256) void k_dinv_scan1(const int* __restrict__ deg,
                                                    float* __restrict__ dinv,
                                                    int* __restrict__ bsum, int n) {
    __shared__ int red[256];
    int b = blockIdx.x, t = threadIdx.x;
    int base = b * 1024 + t * 4;
    int s = 0;
#pragma unroll
    for (int j = 0; j < 4; ++j) {
        int i = base + j;
        if (i < n) { int d = deg[i]; s += d; dinv[i] = rsqrtf((float)(d + 1)); }
    }
    red[t] = s;
    __syncthreads();
    for (int d = 128; d > 0; d >>= 1) {
        if (t < d) red[t] += red[t + d];
        __syncthreads();
    }
    if (t == 0) bsum[b] = red[0];
}

// fused scan2+scan3: every block redundantly scans bsum (<=256 entries) in
// LDS for its own exclusive offset, then block-local scan -> rowPtr.
__global__ __launch_bounds__(256) void k_scan3f(const int* __restrict__ deg,
                                                const int* __restrict__ bsum, int nb,
                                                int* __restrict__ rowPtr, int n) {
    __shared__ int red[256];
    __shared__ int boff[256];
    int b = blockIdx.x, t = threadIdx.x;
    int base = b * 1024 + t * 4;
    int v[4]; int s = 0;
#pragma unroll
    for (int j = 0; j < 4; ++j) { int i = base + j; v[j] = (i < n) ? deg[i] : 0; s += v[j]; }
    red[t] = s;
    boff[t] = (t < nb) ? bsum[t] : 0;
    __syncthreads();
    for (int d = 1; d < 256; d <<= 1) {   // Hillis-Steele inclusive, both arrays
        int u  = (t >= d) ? red[t - d]  : 0;
        int u2 = (t >= d) ? boff[t - d] : 0;
        __syncthreads();
        red[t] += u;
        boff[t] += u2;
        __syncthreads();
    }
    int blockOff = (b == 0) ? 0 : boff[b - 1];          // exclusive block offset
    if (b == 0 && t == 0) rowPtr[n] = boff[nb - 1];     // total = E
    int run = blockOff + red[t] - s;
#pragma unroll
    for (int j = 0; j < 4; ++j) {
        int i = base + j;
        if (i < n) { rowPtr[i] = run; run += v[j]; }
    }
}

// ------- atomic-free edge scatter: edata[rowPtr[d]+rank[e]] = {src,nrm} ---
__global__ __launch_bounds__(256) void k_scatter(
        const int* __restrict__ src, const int* __restrict__ dst,
        const int* __restrict__ rank, const int* __restrict__ rowPtr,
        const float* __restrict__ dinv, int2* __restrict__ edata, int E) {
    int i = (blockIdx.x * 256 + threadIdx.x) * 4;
    if (i + 4 <= E) {
        int4 s4 = *(const int4*)(src + i);
        int4 d4 = *(const int4*)(dst + i);
        int4 r4 = *(const int4*)(rank + i);
        int p0 = rowPtr[d4.x] + r4.x, p1 = rowPtr[d4.y] + r4.y;
        int p2 = rowPtr[d4.z] + r4.z, p3 = rowPtr[d4.w] + r4.w;
        int2 e0; e0.x = s4.x; e0.y = __float_as_int(dinv[s4.x] * dinv[d4.x]);
        int2 e1; e1.x = s4.y; e1.y = __float_as_int(dinv[s4.y] * dinv[d4.y]);
        int2 e2; e2.x = s4.z; e2.y = __float_as_int(dinv[s4.z] * dinv[d4.z]);
        int2 e3; e3.x = s4.w; e3.y = __float_as_int(dinv[s4.w] * dinv[d4.w]);
        edata[p0] = e0; edata[p1] = e1; edata[p2] = e2; edata[p3] = e3;
    } else {
        for (int j = 0; j < 4; ++j) {
            int e = i + j;
            if (e >= E) break;
            int s = src[e], d = dst[e];
            int2 p; p.x = s; p.y = __float_as_int(dinv[s] * dinv[d]);
            edata[rowPtr[d] + rank[e]] = p;
        }
    }
}

// ------- packed-A GEMM (layer 2, bf16 out) --------------------------------
template <int KSTEPS, int NTILES>
__global__ __launch_bounds__(256) void k_gemm_p(
        const bf16_t* __restrict__ Ap, const bf16_t* __restrict__ Bp,
        bf16_t* __restrict__ C, int M) {
    int wave = (blockIdx.x * blockDim.x + threadIdx.x) >> 6;
    if (wave * 16 >= M) return;
    int lane = threadIdx.x & 63;
    int r16 = lane & 15, quad = lane >> 4;
    const int N = NTILES * 16;
    f32x4 acc[NTILES] = {};
    const bf16_t* apb = Ap + (size_t)wave * (KSTEPS * 512) + lane * 8;
#pragma unroll
    for (int s = 0; s < KSTEPS; ++s) {
        bf16x8 a = *(const bf16x8*)(apb + s * 512);
        const bf16_t* bp = Bp + ((size_t)(s * NTILES) * 64 + lane) * 8;
#pragma unroll
        for (int t = 0; t < NTILES; ++t) {
            bf16x8 b = *(const bf16x8*)(bp + t * 512);
            acc[t] = __builtin_amdgcn_mfma_f32_16x16x32_bf16(a, b, acc[t], 0, 0, 0);
        }
    }
#pragma unroll
    for (int t = 0; t < NTILES; ++t)
#pragma unroll
        for (int r = 0; r < 4; ++r)
            C[(size_t)(wave * 16 + quad * 4 + r) * N + t * 16 + r16] = (bf16_t)acc[t][r];
}

// ------- layer-1 aggregate over fp8 XW1 rows (128B), packed Hp out --------
__global__ __launch_bounds__(256) void k_agg1(
        const int* __restrict__ rowPtr, const int2* __restrict__ edata,
        const unsigned char* __restrict__ XW1, const float* __restrict__ dinv,
        const float* __restrict__ b1, bf16_t* __restrict__ Hp, int n) {
    int wave = (blockIdx.x * blockDim.x + threadIdx.x) >> 6;
    if (wave >= n) return;
    int lane = threadIdx.x & 63;
    int fl = (lane & 15) << 3;   // 8 features (bytes, 1B/feat)
    int h  = lane >> 4;          // parity stream 0..3
    int r0 = rowPtr[wave], r1 = rowPtr[wave + 1];
    // self-term preload (independent, hides under the gather loop)
    float d = dinv[wave], d2 = d * d;
    uint2 us = *(const uint2*)(XW1 + (size_t)wave * 128 + fl);
    float a0[8] = {}, a1[8] = {};
    int k = r0 + h;
    for (; k + 4 < r1; k += 8) {          // 2 independent gathers in flight
        int2 e0 = edata[k], e1 = edata[k + 4];
        float w0 = __int_as_float(e0.y), w1 = __int_as_float(e1.y);
        uint2 u0 = *(const uint2*)(XW1 + (size_t)e0.x * 128 + fl);
        uint2 u1 = *(const uint2*)(XW1 + (size_t)e1.x * 128 + fl);
        fma8_fp8(u0, w0, a0);
        fma8_fp8(u1, w1, a1);
    }
    if (k < r1) {
        int2 e0 = edata[k];
        float w0 = __int_as_float(e0.y);
        uint2 u0 = *(const uint2*)(XW1 + (size_t)e0.x * 128 + fl);
        fma8_fp8(u0, w0, a0);
    }
#pragma unroll
    for (int j = 0; j < 8; ++j) {        // convergent reduction over 4 streams
        a0[j] += a1[j];
        a0[j] += __shfl_xor(a0[j], 16);
        a0[j] += __shfl_xor(a0[j], 32);
    }
    if (h == 0) {
        fma8_fp8(us, d2, a0);            // self term
        bf16x8 hv;
#pragma unroll
        for (int j = 0; j < 8; ++j) {
            float v = a0[j] + b1[fl + j];
            hv[j] = (bf16_t)fmaxf(v, 0.f);
        }
        int q = lane & 15;
        size_t off = (((size_t)(wave >> 4) * 4 + (q >> 2)) * 64
                      + (wave & 15) + 16 * (q & 3)) * 8;
        *(bf16x8*)(Hp + off) = hv;
    }
}

// ------- layer-2 aggregate + log_softmax (bf16 XW2) -----------------------
__global__ __launch_bounds__(256) void k_agg2(
        const int* __restrict__ rowPtr, const int2* __restrict__ edata,
        const bf16_t* __restrict__ XW2, const float* __restrict__ dinv,
        const float* __restrict__ b2, float* __restrict__ out, int n) {
    int wave = (blockIdx.x * blockDim.x + threadIdx.x) >> 6;
    if (wave >= n) return;
    int lane = threadIdx.x & 63;
    int g = lane & 15;           // class pair: {2g, 2g+1}
    int h = lane >> 4;           // stream 0..3
    int r0 = rowPtr[wave], r1 = rowPtr[wave + 1];
    // self-term preload
    float d = dinv[wave], d2 = d * d;
    unsigned ps = *(const unsigned*)(XW2 + ((size_t)wave << 5) + 2 * g);
    float2 bb = *(const float2*)(b2 + 2 * g);
    float a00 = 0.f, a01 = 0.f, a10 = 0.f, a11 = 0.f;
    int k = r0 + h;
    for (; k + 4 < r1; k += 8) {
        int2 e0 = edata[k], e1 = edata[k + 4];
        float w0 = __int_as_float(e0.y), w1 = __int_as_float(e1.y);
        unsigned p0 = *(const unsigned*)(XW2 + ((size_t)e0.x << 5) + 2 * g);
        unsigned p1 = *(const unsigned*)(XW2 + ((size_t)e1.x << 5) + 2 * g);
        a00 += __int_as_float(p0 << 16) * w0;
        a01 += __int_as_float(p0 & 0xffff0000u) * w0;
        a10 += __int_as_float(p1 << 16) * w1;
        a11 += __int_as_float(p1 & 0xffff0000u) * w1;
    }
    if (k < r1) {
        int2 e0 = edata[k];
        float w0 = __int_as_float(e0.y);
        unsigned p0 = *(const unsigned*)(XW2 + ((size_t)e0.x << 5) + 2 * g);
        a00 += __int_as_float(p0 << 16) * w0;
        a01 += __int_as_float(p0 & 0xffff0000u) * w0;
    }
    float v0 = a00 + a10, v1 = a01 + a11;
    v0 += __shfl_xor(v0, 16); v0 += __shfl_xor(v0, 32);   // combine 4 streams
    v1 += __shfl_xor(v1, 16); v1 += __shfl_xor(v1, 32);
    v0 += __int_as_float(ps << 16) * d2 + bb.x;
    v1 += __int_as_float(ps & 0xffff0000u) * d2 + bb.y;
    float mx = fmaxf(v0, v1);
#pragma unroll
    for (int m = 8; m >= 1; m >>= 1) mx = fmaxf(mx, __shfl_xor(mx, m));
    float s = __expf(v0 - mx) + __expf(v1 - mx);
#pragma unroll
    for (int m = 8; m >= 1; m >>= 1) s += __shfl_xor(s, m);
    if (h == 0) {
        float ls = __logf(s);
        float2 o; o.x = v0 - mx - ls; o.y = v1 - mx - ls;
        *(float2*)(out + ((size_t)wave << 5) + 2 * g) = o;
    }
}

extern "C" void kernel_launch(void* const* d_in, const int* in_sizes, int n_in,
                              void* d_out, int out_size, void* d_ws, size_t ws_size,
                              hipStream_t stream) {
    const float* feat = (const float*)d_in[0];
    const int*   eidx = (const int*)d_in[1];
    const float* W1   = (const float*)d_in[2];
    const float* b1   = (const float*)d_in[3];
    const float* W2   = (const float*)d_in[4];
    const float* b2   = (const float*)d_in[5];
    float* out = (float*)d_out;

    const int FIN = 256, HID = 128, NCLS = 32;
    const int N = in_sizes[0] / FIN;   // 100000
    const int E = in_sizes[1] / 2;     // 800000
    const int* src = eidx;
    const int* dst = eidx + E;

    // workspace carve-up (256B aligned)
    char* ws = (char*)d_ws;
    size_t o = 0;
    auto alloc = [&](size_t bytes) -> void* {
        void* p = ws + o;
        o = (o + bytes + 255) & ~(size_t)255;
        return p;
    };
    int*    deg    = (int*)   alloc((size_t)N * 4);
    int*    rank   = (int*)   alloc((size_t)E * 4);         // 3.2 MB edge ranks
    float*  dinv   = (float*) alloc((size_t)N * 4);
    int*    rowPtr = (int*)   alloc((size_t)(N + 1) * 4);
    int*    bsum   = (int*)   alloc(256 * 4);
    bf16_t* Bp1    = (bf16_t*)alloc((size_t)(FIN / 32) * (HID / 16) * 512 * 2);
    bf16_t* Bp2    = (bf16_t*)alloc((size_t)(HID / 32) * (NCLS / 16) * 512 * 2);
    int2*   edata  = (int2*)  alloc((size_t)E * 8);         // 6.4 MB
    unsigned char* XW1 = (unsigned char*)alloc((size_t)N * HID);  // 12.8 MB fp8
    bf16_t* Hp     = (bf16_t*)alloc((size_t)N * HID * 2);   // 25.6 MB packed H
    bf16_t* XW2    = (bf16_t*)XW1;  // alias: XW1 dead after k_agg1 (6.4 <= 12.8 MB)

    const int T = 256;
    const int NB = (N + 1023) >> 10;                 // 98 scan blocks (<=256)
    const int DEGB  = (E + 1023) / 1024;             // 782 (4 edges/thread)
    const int GEMMB = (((N + 15) / 16) * 64 + T - 1) / T;   // 1563
    const int PACKB = (32768 + 4096) / 256;          // 144
    const int ZB    = (N + 1023) / 1024;             // 98 deg-zero blocks

    k_prep      <<<PACKB + ZB, T, 0, stream>>>(W1, Bp1, W2, Bp2, deg, N);
    k_front<8, 8><<<DEGB + GEMMB, T, 0, stream>>>(
        feat, Bp1, XW1, N, dst, deg, rank, E, DEGB);
    k_dinv_scan1<<<NB, T, 0, stream>>>(deg, dinv, bsum, N);
    k_scan3f    <<<NB, T, 0, stream>>>(deg, bsum, NB, rowPtr, N);
    k_scatter   <<<(E + 1023) / 1024, T, 0, stream>>>(src, dst, rank, rowPtr, dinv, edata, E);
    k_agg1<<<(N * 64 + T - 1) / T, T, 0, stream>>>(rowPtr, edata, XW1, dinv, b1, Hp, N);
    // layer 2: XW2 = bf16(Hp @ W2), A packed
    {
        int waves = (N + 15) / 16;
        k_gemm_p<4, 2><<<(waves * 64 + T - 1) / T, T, 0, stream>>>(Hp, Bp2, XW2, N);
    }
    k_agg2<<<(N * 64 + T - 1) / T, T, 0, stream>>>(rowPtr, edata, XW2, dinv, b2, out, N);
}